// Round 4
// baseline (3154.433 us; speedup 1.0000x reference)
//
#include <hip/hip_runtime.h>

#define B_ 128
#define T_ 270
#define XR 4104   // 8 + 64*64
#define H_ 256

typedef __attribute__((ext_vector_type(8))) short short8v;
typedef __attribute__((ext_vector_type(4))) float f32x4;

__device__ inline unsigned short f2bf(float f) {
  unsigned u = __builtin_bit_cast(unsigned, f);
  u += 0x7fffu + ((u >> 16) & 1u);
  return (unsigned short)(u >> 16);
}
__device__ inline float sigm(float x) { return 1.0f / (1.0f + __expf(-x)); }
__device__ inline float tanh_f(float x) {
  float t = __expf(-2.0f * fabsf(x));
  float r = (1.0f - t) / (1.0f + t);
  return copysignf(r, x);
}

// ---------------------------------------------------------------------------
// Kernel 1: per-(b,t) CNN tower. One block per image. (unchanged logic)
// ---------------------------------------------------------------------------
__global__ __launch_bounds__(256) void cnn_kernel(
    const float* __restrict__ x,
    const float* __restrict__ c1w_, const float* __restrict__ c1b_,
    const float* __restrict__ c2w_, const float* __restrict__ c2b_,
    const float* __restrict__ fcw, const float* __restrict__ fcb,
    float* __restrict__ feat)
{
  __shared__ float img[64 * 68];
  __shared__ float p1[2 * 15 * 16];
  __shared__ float p2[36];
  __shared__ float wsm[96];
  const int tid = threadIdx.x;
  const int bt = blockIdx.x;
  const int b = bt & 127, t = bt >> 7;

  const float* src = x + ((long)b * T_ + t) * XR;

  if (tid < 18) wsm[tid] = c1w_[tid];
  else if (tid < 20) wsm[tid] = c1b_[tid - 18];
  else if (tid < 92) wsm[tid] = c2w_[tid - 20];
  else if (tid < 96) wsm[tid] = c2b_[tid - 92];

  {
    const float4* s4 = (const float4*)(src + 8);
#pragma unroll
    for (int i0 = 0; i0 < 4; i0++) {
      int i = tid + i0 * 256;
      float4 v = s4[i];
      int e = i * 4;
      *((float4*)&img[(e >> 6) * 68 + (e & 63)]) = v;
    }
  }
  __syncthreads();

  if (tid < 225) {
    int py = tid / 15, px = tid - (tid / 15) * 15;
    float w0[9], w1[9];
#pragma unroll
    for (int j = 0; j < 9; j++) { w0[j] = wsm[j]; w1[j] = wsm[9 + j]; }
    const float b0 = wsm[18], b1v = wsm[19];
    float m0 = -1e30f, m1 = -1e30f;
    for (int dy = 0; dy < 4; dy++) {
      for (int dx = 0; dx < 4; dx++) {
        const float* ip = &img[(py * 4 + dy) * 68 + px * 4 + dx];
        float s0 = b0, s1 = b1v;
#pragma unroll
        for (int ky = 0; ky < 3; ky++) {
#pragma unroll
          for (int kx = 0; kx < 3; kx++) {
            float v = ip[ky * 68 + kx];
            s0 = fmaf(v, w0[ky * 3 + kx], s0);
            s1 = fmaf(v, w1[ky * 3 + kx], s1);
          }
        }
        m0 = fmaxf(m0, s0); m1 = fmaxf(m1, s1);
      }
    }
    p1[py * 16 + px] = fmaxf(m0, 0.f);
    p1[240 + py * 16 + px] = fmaxf(m1, 0.f);
  }
  __syncthreads();

  if (tid < 36) {
    int ch = tid / 9, rem = tid - ch * 9;
    int py = rem / 3, px = rem - py * 3;
    float m = -1e30f;
    for (int dy = 0; dy < 4; dy++) {
      for (int dx = 0; dx < 4; dx++) {
        int y = py * 4 + dy, xx = px * 4 + dx;
        float s = wsm[92 + ch];
#pragma unroll
        for (int ic = 0; ic < 2; ic++)
#pragma unroll
          for (int ky = 0; ky < 3; ky++)
#pragma unroll
            for (int kx = 0; kx < 3; kx++)
              s = fmaf(p1[ic * 240 + (y + ky) * 16 + xx + kx],
                       wsm[20 + ((ch * 2 + ic) * 3 + ky) * 3 + kx], s);
        m = fmaxf(m, s);
      }
    }
    p2[tid] = fmaxf(m, 0.f);
  }
  __syncthreads();

  float* fr = feat + ((long)t * B_ + b) * 16;
  if (tid < 8) {
    float s = fcb[tid];
#pragma unroll
    for (int j = 0; j < 36; j++) s = fmaf(p2[j], fcw[tid * 36 + j], s);
    fr[8 + tid] = s;
  } else if (tid < 16) {
    fr[tid - 8] = src[tid - 8];
  }
}

// ---------------------------------------------------------------------------
// Kernel 2: LSTM recurrence, ZERO inter-block communication.
// 8 blocks = 8 batch groups of 16 rows; each block computes the FULL hidden
// state for its rows. 512 threads = 8 waves; wave w owns h-dims w*32..+31
// for ALL FOUR gates -> i,f,g,o of every cell live in the same lane's acc,
// so the LSTM elementwise runs in-register (no gates LDS round-trip).
// h is exchanged through an XOR-swizzled LDS buffer (T2: row stride 512B
// would be a 16-way bank conflict; byte ^= (row&7)<<4 on both sides).
// Head projection fused: shuffle-reduce + per-wave LDS partials + 16 plain
// stores/step. No atomics, no fences, no flags anywhere.
// B-frags: 8 (gate,q) x 9 K-frags = 288 VGPR, all indices compile-time.
// ---------------------------------------------------------------------------
__global__ __launch_bounds__(512, 1) void lstm_kernel(
    const float* __restrict__ feat, const float* __restrict__ whh,
    const float* __restrict__ wih, const float* __restrict__ bih,
    const float* __restrict__ bhh, const float* __restrict__ h0,
    const float* __restrict__ c0, const float* __restrict__ hw,
    const float* __restrict__ hdb, float* __restrict__ out)
{
  const int tid = threadIdx.x;
  const int w = tid >> 6, lane = tid & 63;
  const int R0 = blockIdx.x * 16;          // batch rows R0..R0+15
  const int col15 = lane & 15;             // B col / A row / D col
  const int ko8 = (lane >> 4) * 8;         // K offset within a 32-K frag
  const int rb = (lane >> 4) * 4;          // D row base
  const int Dw = w * 32;                   // wave's h-dim base

  __shared__ unsigned short hls[16 * 256]; // h(t) bf16, XOR-swizzled
  __shared__ float headp[8][20];           // per-wave head partials [wave][row]

  // ---- B-fragments: bf[g*2+q][kf], col = g*256 + Dw + q*16 + col15
  short8v bf[8][9];
#pragma unroll
  for (int g = 0; g < 4; g++) {
#pragma unroll
    for (int q = 0; q < 2; q++) {
      const int col = g * 256 + Dw + q * 16 + col15;
      const float* wr = whh + col * 256;
#pragma unroll
      for (int kf = 0; kf < 8; kf++) {
        const float4* wp = (const float4*)(wr + kf * 32 + ko8);
        float4 a = wp[0], bq = wp[1];
        short8v v;
        v[0] = f2bf(a.x); v[1] = f2bf(a.y); v[2] = f2bf(a.z); v[3] = f2bf(a.w);
        v[4] = f2bf(bq.x); v[5] = f2bf(bq.y); v[6] = f2bf(bq.z); v[7] = f2bf(bq.w);
        bf[g * 2 + q][kf] = v;
      }
      short8v v = {0, 0, 0, 0, 0, 0, 0, 0};
      if (ko8 < 16) {   // w_ih occupies K-slots 0..15 of the feat fragment
        const float4* wp = (const float4*)(wih + col * 16 + ko8);
        float4 a = wp[0], bq = wp[1];
        v[0] = f2bf(a.x); v[1] = f2bf(a.y); v[2] = f2bf(a.z); v[3] = f2bf(a.w);
        v[4] = f2bf(bq.x); v[5] = f2bf(bq.y); v[6] = f2bf(bq.z); v[7] = f2bf(bq.w);
      }
      bf[g * 2 + q][8] = v;
    }
  }

  // ---- per-lane constants: biases (per gate-col), head weights
  float bsr[8];
#pragma unroll
  for (int g = 0; g < 4; g++)
#pragma unroll
    for (int q = 0; q < 2; q++) {
      const int col = g * 256 + Dw + q * 16 + col15;
      bsr[g * 2 + q] = bih[col] + bhh[col];
    }
  float hwr[2] = { hw[Dw + col15], hw[Dw + 16 + col15] };
  const float hdb0 = hdb[0];

  // ---- c-state in registers; h0 -> swizzled LDS
  float cs[2][4];
#pragma unroll
  for (int q = 0; q < 2; q++)
#pragma unroll
    for (int rr = 0; rr < 4; rr++) {
      const int row = rb + rr, dim = Dw + q * 16 + col15;
      cs[q][rr] = c0[(R0 + row) * H_ + dim];
      const int byte = (row * 512 + dim * 2) ^ ((row & 7) << 4);
      *(unsigned short*)((char*)hls + byte) = f2bf(h0[(R0 + row) * H_ + dim]);
    }
  __syncthreads();

  const int ar = col15;   // A-fragment row
  for (int t = 0; t < T_; t++) {
    // ---- A-fragments: h(t) from swizzled LDS + feat from global (L2)
    short8v af[9];
#pragma unroll
    for (int kf = 0; kf < 8; kf++) {
      const int byte = (ar * 512 + kf * 64 + ko8 * 2) ^ ((ar & 7) << 4);
      af[kf] = *(const short8v*)((const char*)hls + byte);
    }
    {
      short8v v = {0, 0, 0, 0, 0, 0, 0, 0};
      if (ko8 < 16) {
        const float4* fp = (const float4*)(feat + ((long)t * B_ + R0 + ar) * 16 + ko8);
        float4 a = fp[0], bq = fp[1];
        v[0] = f2bf(a.x); v[1] = f2bf(a.y); v[2] = f2bf(a.z); v[3] = f2bf(a.w);
        v[4] = f2bf(bq.x); v[5] = f2bf(bq.y); v[6] = f2bf(bq.z); v[7] = f2bf(bq.w);
      }
      af[8] = v;
    }

    // ---- head output for step t-1 (headp written before last barrier)
    if (w == 0 && lane < 16 && t > 0) {
      float s = hdb0;
#pragma unroll
      for (int i = 0; i < 8; i++) s += headp[i][lane];
      out[(long)(R0 + lane) * T_ + (t - 1)] = s;
    }
    __syncthreads();   // all h(t) reads done; headp(t-1) consumed

    // ---- 72 MFMAs: 8 independent acc chains of depth 9
    f32x4 acc[8];
#pragma unroll
    for (int u = 0; u < 8; u++) acc[u] = (f32x4){0.f, 0.f, 0.f, 0.f};
#pragma unroll
    for (int kf = 0; kf < 9; kf++)
#pragma unroll
      for (int u = 0; u < 8; u++)
        acc[u] = __builtin_amdgcn_mfma_f32_16x16x32_bf16(af[kf], bf[u][kf], acc[u], 0, 0, 0);

    // ---- in-register LSTM cell (i,f,g,o all local) + h publish + head partial
    float ps[4] = {0.f, 0.f, 0.f, 0.f};
#pragma unroll
    for (int q = 0; q < 2; q++)
#pragma unroll
      for (int rr = 0; rr < 4; rr++) {
        float i_ = acc[0 + q][rr] + bsr[0 + q];
        float f_ = acc[2 + q][rr] + bsr[2 + q];
        float g_ = acc[4 + q][rr] + bsr[4 + q];
        float o_ = acc[6 + q][rr] + bsr[6 + q];
        float cn = sigm(f_) * cs[q][rr] + sigm(i_) * tanh_f(g_);
        cs[q][rr] = cn;
        float hn = sigm(o_) * tanh_f(cn);
        const int row = rb + rr, dim = Dw + q * 16 + col15;
        const int byte = (row * 512 + dim * 2) ^ ((row & 7) << 4);
        *(unsigned short*)((char*)hls + byte) = f2bf(hn);
        ps[rr] += hn * hwr[q];
      }
    // reduce head partials over the 16 lanes of each row group
#pragma unroll
    for (int off = 1; off <= 8; off <<= 1)
#pragma unroll
      for (int rr = 0; rr < 4; rr++) ps[rr] += __shfl_xor(ps[rr], off);
    if (col15 == 0)
#pragma unroll
      for (int rr = 0; rr < 4; rr++) headp[w][rb + rr] = ps[rr];
    __syncthreads();   // h(t+1) + headp(t) visible to all waves
  }

  // ---- final head output (t = T-1)
  if (w == 0 && lane < 16) {
    float s = hdb0;
#pragma unroll
    for (int i = 0; i < 8; i++) s += headp[i][lane];
    out[(long)(R0 + lane) * T_ + (T_ - 1)] = s;
  }
}

// ---------------------------------------------------------------------------
extern "C" void kernel_launch(void* const* d_in, const int* in_sizes, int n_in,
                              void* d_out, int out_size, void* d_ws, size_t ws_size,
                              hipStream_t stream) {
  const float* x   = (const float*)d_in[0];
  const float* c1w = (const float*)d_in[1];
  const float* c1b = (const float*)d_in[2];
  const float* c2w = (const float*)d_in[3];
  const float* c2b = (const float*)d_in[4];
  const float* fcw = (const float*)d_in[5];
  const float* fcb = (const float*)d_in[6];
  const float* wih = (const float*)d_in[7];
  const float* whh = (const float*)d_in[8];
  const float* bih = (const float*)d_in[9];
  const float* bhh = (const float*)d_in[10];
  const float* hw  = (const float*)d_in[11];
  const float* hdb = (const float*)d_in[12];
  const float* h0  = (const float*)d_in[13];
  const float* c0  = (const float*)d_in[14];
  float* out = (float*)d_out;

  // workspace: feat fp32 [270][128][16] only (2.21 MB)
  float* feat = (float*)d_ws;

  cnn_kernel<<<dim3(B_ * T_), dim3(256), 0, stream>>>(
      x, c1w, c1b, c2w, c2b, fcw, fcb, feat);
  lstm_kernel<<<dim3(8), dim3(512), 0, stream>>>(
      feat, whh, wih, bih, bhh, h0, c0, hw, hdb, out);
}

// Round 5
// 2214.077 us; speedup vs baseline: 1.4247x; 1.4247x over previous
//
#include <hip/hip_runtime.h>

#define B_ 128
#define T_ 270
#define XR 4104   // 8 + 64*64
#define H_ 256

#define LDSB_BYTES 147456          // 8 waves * 18 slots * 64 lanes * 16 B
#define HLS_STRIDE 264             // shorts per h row (528 B = 33*16, pad kills bank conflicts)
#define HLS_BYTES  (16 * HLS_STRIDE * 2)          // 8448
#define SMEM_TOTAL (LDSB_BYTES + HLS_BYTES + 8 * 20 * 4)   // 156544
#define SPACK_SHORTS (8 * 14 * 64 * 8)            // 57344 shorts = 114688 B

typedef __attribute__((ext_vector_type(8))) short short8v;
typedef __attribute__((ext_vector_type(4))) float f32x4;

__device__ inline unsigned short f2bf(float f) {
  unsigned u = __builtin_bit_cast(unsigned, f);
  u += 0x7fffu + ((u >> 16) & 1u);
  return (unsigned short)(u >> 16);
}
__device__ inline float sigm(float x) { return 1.0f / (1.0f + __expf(-x)); }
__device__ inline float tanh_f(float x) {
  float t = __expf(-2.0f * fabsf(x));
  float r = (1.0f - t) / (1.0f + t);
  return copysignf(r, x);
}
__device__ inline short8v pack8(const float* p) {
  float4 a = *(const float4*)p, b = *(const float4*)(p + 4);
  short8v v;
  v[0] = (short)f2bf(a.x); v[1] = (short)f2bf(a.y);
  v[2] = (short)f2bf(a.z); v[3] = (short)f2bf(a.w);
  v[4] = (short)f2bf(b.x); v[5] = (short)f2bf(b.y);
  v[6] = (short)f2bf(b.z); v[7] = (short)f2bf(b.w);
  return v;
}
__device__ inline short8v ntl(const unsigned short* p) {
  return __builtin_nontemporal_load((const short8v*)p);
}
#define MFMA(a, b, c) __builtin_amdgcn_mfma_f32_16x16x32_bf16((a), (b), (c), 0, 0, 0)

// ---------------------------------------------------------------------------
// Kernel 1: per-(b,t) CNN tower. One block per image. (unchanged logic)
// ---------------------------------------------------------------------------
__global__ __launch_bounds__(256) void cnn_kernel(
    const float* __restrict__ x,
    const float* __restrict__ c1w_, const float* __restrict__ c1b_,
    const float* __restrict__ c2w_, const float* __restrict__ c2b_,
    const float* __restrict__ fcw, const float* __restrict__ fcb,
    float* __restrict__ feat)
{
  __shared__ float img[64 * 68];
  __shared__ float p1[2 * 15 * 16];
  __shared__ float p2[36];
  __shared__ float wsm[96];
  const int tid = threadIdx.x;
  const int bt = blockIdx.x;
  const int b = bt & 127, t = bt >> 7;

  const float* src = x + ((long)b * T_ + t) * XR;

  if (tid < 18) wsm[tid] = c1w_[tid];
  else if (tid < 20) wsm[tid] = c1b_[tid - 18];
  else if (tid < 92) wsm[tid] = c2w_[tid - 20];
  else if (tid < 96) wsm[tid] = c2b_[tid - 92];

  {
    const float4* s4 = (const float4*)(src + 8);
#pragma unroll
    for (int i0 = 0; i0 < 4; i0++) {
      int i = tid + i0 * 256;
      float4 v = s4[i];
      int e = i * 4;
      *((float4*)&img[(e >> 6) * 68 + (e & 63)]) = v;
    }
  }
  __syncthreads();

  if (tid < 225) {
    int py = tid / 15, px = tid - (tid / 15) * 15;
    float w0[9], w1[9];
#pragma unroll
    for (int j = 0; j < 9; j++) { w0[j] = wsm[j]; w1[j] = wsm[9 + j]; }
    const float b0 = wsm[18], b1v = wsm[19];
    float m0 = -1e30f, m1 = -1e30f;
    for (int dy = 0; dy < 4; dy++) {
      for (int dx = 0; dx < 4; dx++) {
        const float* ip = &img[(py * 4 + dy) * 68 + px * 4 + dx];
        float s0 = b0, s1 = b1v;
#pragma unroll
        for (int ky = 0; ky < 3; ky++) {
#pragma unroll
          for (int kx = 0; kx < 3; kx++) {
            float v = ip[ky * 68 + kx];
            s0 = fmaf(v, w0[ky * 3 + kx], s0);
            s1 = fmaf(v, w1[ky * 3 + kx], s1);
          }
        }
        m0 = fmaxf(m0, s0); m1 = fmaxf(m1, s1);
      }
    }
    p1[py * 16 + px] = fmaxf(m0, 0.f);
    p1[240 + py * 16 + px] = fmaxf(m1, 0.f);
  }
  __syncthreads();

  if (tid < 36) {
    int ch = tid / 9, rem = tid - ch * 9;
    int py = rem / 3, px = rem - py * 3;
    float m = -1e30f;
    for (int dy = 0; dy < 4; dy++) {
      for (int dx = 0; dx < 4; dx++) {
        int y = py * 4 + dy, xx = px * 4 + dx;
        float s = wsm[92 + ch];
#pragma unroll
        for (int ic = 0; ic < 2; ic++)
#pragma unroll
          for (int ky = 0; ky < 3; ky++)
#pragma unroll
            for (int kx = 0; kx < 3; kx++)
              s = fmaf(p1[ic * 240 + (y + ky) * 16 + xx + kx],
                       wsm[20 + ((ch * 2 + ic) * 3 + ky) * 3 + kx], s);
        m = fmaxf(m, s);
      }
    }
    p2[tid] = fmaxf(m, 0.f);
  }
  __syncthreads();

  float* fr = feat + ((long)t * B_ + b) * 16;
  if (tid < 8) {
    float s = fcb[tid];
#pragma unroll
    for (int j = 0; j < 36; j++) s = fmaf(p2[j], fcw[tid * 36 + j], s);
    fr[8 + tid] = s;
  } else if (tid < 16) {
    fr[tid - 8] = src[tid - 8];
  }
}

// ---------------------------------------------------------------------------
// Kernel 1b: pack the STREAMED weight tier (kf7 cols 2..7, kf8 cols 0..7 per
// wave) into bf16, laid out exactly as the lstm kernel's per-lane dwordx4
// stream loads expect: spack[((w*14+fs)*64+lane)*8 + j].
// ---------------------------------------------------------------------------
__global__ __launch_bounds__(256) void pack_kernel(
    const float* __restrict__ whh, const float* __restrict__ wih,
    unsigned short* __restrict__ spack)
{
  const int idx = blockIdx.x * 256 + threadIdx.x;
  if (idx >= 8 * 14 * 64) return;
  const int lane = idx & 63;
  const int fs = (idx >> 6) % 14;
  const int w = idx / (14 * 64);
  const int col15 = lane & 15, ko8 = (lane >> 4) * 8;
  const int u = (fs < 6) ? fs + 2 : fs - 6;
  const int col = (u >> 1) * 256 + w * 32 + (u & 1) * 16 + col15;
  short8v v = {0, 0, 0, 0, 0, 0, 0, 0};
  if (fs < 6) {                       // kf7: h dims 224..255
    const float* p = whh + col * 256 + 224 + ko8;
    v = pack8(p);
  } else if (ko8 < 16) {              // kf8: w_ih (K 0..15), rest zero
    const float* p = wih + col * 16 + ko8;
    v = pack8(p);
  }
  *(short8v*)(spack + (size_t)idx * 8) = v;
}

// ---------------------------------------------------------------------------
// Kernel 2: LSTM, zero inter-block communication, THREE-TIER weights:
//   VGPR tier : kf0..4  (40 frags/wave = 160 VGPR)  — fits 256-VGPR cap
//               (8-wave block => 2 waves/SIMD => 256 cap; round-4's 288-VGPR
//                design spilled: VGPR_Count 128, 3 us/step scratch-bound)
//   LDS tier  : kf5,6 all cols + kf7 cols 0,1 (18 frags/wave = 144 KB)
//   STREAM    : kf7 cols 2..7 + kf8 (14 frags/wave = 112 KB/step from L2,
//               pre-packed bf16, issued in 4 batches under MFMA cover)
// h lives in LDS with 528-B row stride (16B pad => conflict-free, aligned).
// i,f,g,o of each cell land in the same lane's acc => in-register cell math.
// ---------------------------------------------------------------------------
__global__ __launch_bounds__(512, 2) void lstm_kernel(
    const float* __restrict__ feat, const float* __restrict__ whh,
    const float* __restrict__ wih, const float* __restrict__ bih,
    const float* __restrict__ bhh, const float* __restrict__ h0,
    const float* __restrict__ c0, const float* __restrict__ hw,
    const float* __restrict__ hdb, const unsigned short* __restrict__ spack,
    float* __restrict__ out)
{
  extern __shared__ char smem[];
  unsigned short* ldsB = (unsigned short*)smem;                 // B tier
  unsigned short* hls  = (unsigned short*)(smem + LDSB_BYTES);  // h state
  float* headp = (float*)(smem + LDSB_BYTES + HLS_BYTES);       // [8][20]

  const int tid = threadIdx.x;
  const int w = tid >> 6, lane = tid & 63;
  const int R0 = blockIdx.x * 16;
  const int col15 = lane & 15;
  const int ko8 = (lane >> 4) * 8;
  const int rb = (lane >> 4) * 4;
  const int Dw = w * 32;

  // ---- VGPR-resident B tier: kf0..4, all 8 gate-cols of this wave
  short8v bfr[8][5];
#pragma unroll
  for (int u = 0; u < 8; u++) {
    const int col = (u >> 1) * 256 + Dw + (u & 1) * 16 + col15;
    const float* wr = whh + col * 256;
#pragma unroll
    for (int kf = 0; kf < 5; kf++)
      bfr[u][kf] = pack8(wr + kf * 32 + ko8);
  }

  // ---- LDS B tier: slots 0..7 = kf5, 8..15 = kf6, 16..17 = kf7 cols 0,1
#pragma unroll
  for (int s = 0; s < 18; s++) {
    const int kf = (s < 8) ? 5 : (s < 16) ? 6 : 7;
    const int u = (s < 8) ? s : (s < 16) ? (s - 8) : (s - 16);
    const int col = (u >> 1) * 256 + Dw + (u & 1) * 16 + col15;
    *(short8v*)&ldsB[((w * 18 + s) * 64 + lane) * 8] =
        pack8(whh + col * 256 + kf * 32 + ko8);
  }

  // ---- per-lane constants
  float bsr[8];
#pragma unroll
  for (int u = 0; u < 8; u++) {
    const int col = (u >> 1) * 256 + Dw + (u & 1) * 16 + col15;
    bsr[u] = bih[col] + bhh[col];
  }
  float hwr[2] = { hw[Dw + col15], hw[Dw + 16 + col15] };
  const float hdb0 = hdb[0];

  // ---- c-state in registers; h0 -> padded LDS
  float cs[2][4];
#pragma unroll
  for (int q = 0; q < 2; q++)
#pragma unroll
    for (int rr = 0; rr < 4; rr++) {
      const int row = rb + rr, dim = Dw + q * 16 + col15;
      cs[q][rr] = c0[(R0 + row) * H_ + dim];
      hls[row * HLS_STRIDE + dim] = f2bf(h0[(R0 + row) * H_ + dim]);
    }

  const int ar = col15;  // A-fragment row (batch row in tile)
  const unsigned short* swv = spack + (size_t)(w * 14) * 512 + (size_t)lane * 8;

  for (int t = 0; t < T_; t++) {
    __syncthreads();   // h(t) & headp(t-1) ready (init covered for t=0)

    if (w == 0 && lane < 16 && t > 0) {
      float s = hdb0;
#pragma unroll
      for (int i = 0; i < 8; i++) s += headp[i * 20 + lane];
      out[(long)(R0 + lane) * T_ + (t - 1)] = s;
    }

    // issue stream batch A (kf7, u=2..5)
    short8v sa0 = ntl(swv + 0 * 512), sa1 = ntl(swv + 1 * 512),
            sa2 = ntl(swv + 2 * 512), sa3 = ntl(swv + 3 * 512);

    // feat A-fragment
    short8v af8 = (short8v){0, 0, 0, 0, 0, 0, 0, 0};
    if (ko8 < 16)
      af8 = pack8(feat + ((long)t * B_ + R0 + ar) * 16 + ko8);

    f32x4 acc[8];
#pragma unroll
    for (int u = 0; u < 8; u++) acc[u] = (f32x4){0.f, 0.f, 0.f, 0.f};

    // kf0..4 (register B, JIT A from LDS)
#pragma unroll
    for (int kf = 0; kf < 5; kf++) {
      short8v a = *(const short8v*)&hls[ar * HLS_STRIDE + kf * 32 + ko8];
#pragma unroll
      for (int u = 0; u < 8; u++)
        acc[u] = MFMA(a, bfr[u][kf], acc[u]);
    }

    short8v af7 = *(const short8v*)&hls[ar * HLS_STRIDE + 224 + ko8];

    // consume A: kf7 u2..5
    acc[2] = MFMA(af7, sa0, acc[2]); acc[3] = MFMA(af7, sa1, acc[3]);
    acc[4] = MFMA(af7, sa2, acc[4]); acc[5] = MFMA(af7, sa3, acc[5]);

    // issue batch B (kf7 u6,7 ; kf8 u0,1)
    short8v sb0 = ntl(swv + 4 * 512), sb1 = ntl(swv + 5 * 512),
            sb2 = ntl(swv + 6 * 512), sb3 = ntl(swv + 7 * 512);

    // kf5, kf6 (LDS B)
    {
      short8v a5 = *(const short8v*)&hls[ar * HLS_STRIDE + 5 * 32 + ko8];
#pragma unroll
      for (int u = 0; u < 8; u++) {
        short8v b = *(const short8v*)&ldsB[((w * 18 + u) * 64 + lane) * 8];
        acc[u] = MFMA(a5, b, acc[u]);
      }
      short8v a6 = *(const short8v*)&hls[ar * HLS_STRIDE + 6 * 32 + ko8];
#pragma unroll
      for (int u = 0; u < 8; u++) {
        short8v b = *(const short8v*)&ldsB[((w * 18 + 8 + u) * 64 + lane) * 8];
        acc[u] = MFMA(a6, b, acc[u]);
      }
    }

    // consume B
    acc[6] = MFMA(af7, sb0, acc[6]); acc[7] = MFMA(af7, sb1, acc[7]);
    acc[0] = MFMA(af8, sb2, acc[0]); acc[1] = MFMA(af8, sb3, acc[1]);

    // issue batch C (kf8 u2..5)
    short8v sc0 = ntl(swv + 8 * 512), sc1 = ntl(swv + 9 * 512),
            sc2 = ntl(swv + 10 * 512), sc3 = ntl(swv + 11 * 512);

    // kf7 cols 0,1 (LDS slots 16,17)
    {
      short8v b16 = *(const short8v*)&ldsB[((w * 18 + 16) * 64 + lane) * 8];
      acc[0] = MFMA(af7, b16, acc[0]);
      short8v b17 = *(const short8v*)&ldsB[((w * 18 + 17) * 64 + lane) * 8];
      acc[1] = MFMA(af7, b17, acc[1]);
    }

    // consume C
    acc[2] = MFMA(af8, sc0, acc[2]); acc[3] = MFMA(af8, sc1, acc[3]);
    acc[4] = MFMA(af8, sc2, acc[4]); acc[5] = MFMA(af8, sc3, acc[5]);

    // issue + consume D (kf8 u6,7)
    short8v sd0 = ntl(swv + 12 * 512), sd1 = ntl(swv + 13 * 512);
    acc[6] = MFMA(af8, sd0, acc[6]); acc[7] = MFMA(af8, sd1, acc[7]);

    __syncthreads();   // all reads of h(t)/headp done before overwrite

    // ---- in-register LSTM cell + h publish + head partial
    float ps[4] = {0.f, 0.f, 0.f, 0.f};
#pragma unroll
    for (int q = 0; q < 2; q++)
#pragma unroll
      for (int rr = 0; rr < 4; rr++) {
        float i_ = acc[0 + q][rr] + bsr[0 + q];
        float f_ = acc[2 + q][rr] + bsr[2 + q];
        float g_ = acc[4 + q][rr] + bsr[4 + q];
        float o_ = acc[6 + q][rr] + bsr[6 + q];
        float cn = sigm(f_) * cs[q][rr] + sigm(i_) * tanh_f(g_);
        cs[q][rr] = cn;
        float hn = sigm(o_) * tanh_f(cn);
        const int row = rb + rr, dim = Dw + q * 16 + col15;
        hls[row * HLS_STRIDE + dim] = f2bf(hn);
        ps[rr] += hn * hwr[q];
      }
#pragma unroll
    for (int off = 1; off <= 8; off <<= 1)
#pragma unroll
      for (int rr = 0; rr < 4; rr++) ps[rr] += __shfl_xor(ps[rr], off);
    if (col15 == 0)
#pragma unroll
      for (int rr = 0; rr < 4; rr++) headp[w * 20 + rb + rr] = ps[rr];
  }

  __syncthreads();
  if (w == 0 && lane < 16) {
    float s = hdb0;
#pragma unroll
    for (int i = 0; i < 8; i++) s += headp[i * 20 + lane];
    out[(long)(R0 + lane) * T_ + (T_ - 1)] = s;
  }
}

// ---------------------------------------------------------------------------
extern "C" void kernel_launch(void* const* d_in, const int* in_sizes, int n_in,
                              void* d_out, int out_size, void* d_ws, size_t ws_size,
                              hipStream_t stream) {
  const float* x   = (const float*)d_in[0];
  const float* c1w = (const float*)d_in[1];
  const float* c1b = (const float*)d_in[2];
  const float* c2w = (const float*)d_in[3];
  const float* c2b = (const float*)d_in[4];
  const float* fcw = (const float*)d_in[5];
  const float* fcb = (const float*)d_in[6];
  const float* wih = (const float*)d_in[7];
  const float* whh = (const float*)d_in[8];
  const float* bih = (const float*)d_in[9];
  const float* bhh = (const float*)d_in[10];
  const float* hw  = (const float*)d_in[11];
  const float* hdb = (const float*)d_in[12];
  const float* h0  = (const float*)d_in[13];
  const float* c0  = (const float*)d_in[14];
  float* out = (float*)d_out;

  char* ws = (char*)d_ws;
  const size_t FEAT_B = (size_t)T_ * B_ * 16 * 4;   // 2,211,840
  const size_t SPACK_B = (size_t)SPACK_SHORTS * 2;  // 114,688
  if (ws_size < FEAT_B + SPACK_B) return;
  float* feat = (float*)ws;
  unsigned short* spack = (unsigned short*)(ws + FEAT_B);

  static int smem_cfg = 0;
  if (!smem_cfg) {
    hipFuncSetAttribute((const void*)lstm_kernel,
                        hipFuncAttributeMaxDynamicSharedMemorySize, SMEM_TOTAL);
    smem_cfg = 1;
  }

  cnn_kernel<<<dim3(B_ * T_), dim3(256), 0, stream>>>(
      x, c1w, c1b, c2w, c2b, fcw, fcb, feat);
  pack_kernel<<<dim3(28), dim3(256), 0, stream>>>(whh, wih, spack);
  lstm_kernel<<<dim3(8), dim3(512), SMEM_TOTAL, stream>>>(
      feat, whh, wih, bih, bhh, h0, c0, hw, hdb, spack, out);
}

// Round 6
// 2082.384 us; speedup vs baseline: 1.5148x; 1.0632x over previous
//
#include <hip/hip_runtime.h>

#define B_ 128
#define T_ 270
#define XR 4104   // 8 + 64*64
#define H_ 256

#define LDSB_BYTES 147456          // 8 waves * 18 slots * 64 lanes * 16 B
#define HLS_STRIDE 264             // shorts per h row (528 B, 16B pad: conflict-free)
#define HLS_BYTES  (16 * HLS_STRIDE * 2)                   // 8448
#define SMEM_TOTAL (LDSB_BYTES + HLS_BYTES + 8 * 20 * 4)   // 156544
#define SPACK_SHORTS (8 * 8 * 9 * 64 * 8)                  // 294912 shorts = 576 KB

typedef __attribute__((ext_vector_type(8))) short short8v;
typedef __attribute__((ext_vector_type(4))) float f32x4;

__device__ inline unsigned short f2bf(float f) {
  unsigned u = __builtin_bit_cast(unsigned, f);
  u += 0x7fffu + ((u >> 16) & 1u);
  return (unsigned short)(u >> 16);
}
__device__ inline float sigm(float x) { return 1.0f / (1.0f + __expf(-x)); }
__device__ inline float tanh_f(float x) {
  float t = __expf(-2.0f * fabsf(x));
  float r = (1.0f - t) / (1.0f + t);
  return copysignf(r, x);
}
__device__ inline short8v pack8(const float* p) {
  float4 a = *(const float4*)p, b = *(const float4*)(p + 4);
  short8v v;
  v[0] = (short)f2bf(a.x); v[1] = (short)f2bf(a.y);
  v[2] = (short)f2bf(a.z); v[3] = (short)f2bf(a.w);
  v[4] = (short)f2bf(b.x); v[5] = (short)f2bf(b.y);
  v[6] = (short)f2bf(b.z); v[7] = (short)f2bf(b.w);
  return v;
}
// Non-rematerializable identity: values become asm-defined, so LLVM must keep
// them live (or spill) instead of re-executing the load+cvt chain per step
// (round-5 pathology: VGPR_Count 128, VALU-storm remat of pack8(whh)).
__device__ inline short8v pinned(short8v v) {
  union { short8v s; float f[4]; } u;
  u.s = v;
  asm volatile("" : "+v"(u.f[0]), "+v"(u.f[1]), "+v"(u.f[2]), "+v"(u.f[3]));
  return u.s;
}
#define MFMA(a, b, c) __builtin_amdgcn_mfma_f32_16x16x32_bf16((a), (b), (c), 0, 0, 0)

// ---------------------------------------------------------------------------
// Kernel 1: per-(b,t) CNN tower. One block per image. (unchanged)
// ---------------------------------------------------------------------------
__global__ __launch_bounds__(256) void cnn_kernel(
    const float* __restrict__ x,
    const float* __restrict__ c1w_, const float* __restrict__ c1b_,
    const float* __restrict__ c2w_, const float* __restrict__ c2b_,
    const float* __restrict__ fcw, const float* __restrict__ fcb,
    float* __restrict__ feat)
{
  __shared__ float img[64 * 68];
  __shared__ float p1[2 * 15 * 16];
  __shared__ float p2[36];
  __shared__ float wsm[96];
  const int tid = threadIdx.x;
  const int bt = blockIdx.x;
  const int b = bt & 127, t = bt >> 7;

  const float* src = x + ((long)b * T_ + t) * XR;

  if (tid < 18) wsm[tid] = c1w_[tid];
  else if (tid < 20) wsm[tid] = c1b_[tid - 18];
  else if (tid < 92) wsm[tid] = c2w_[tid - 20];
  else if (tid < 96) wsm[tid] = c2b_[tid - 92];

  {
    const float4* s4 = (const float4*)(src + 8);
#pragma unroll
    for (int i0 = 0; i0 < 4; i0++) {
      int i = tid + i0 * 256;
      float4 v = s4[i];
      int e = i * 4;
      *((float4*)&img[(e >> 6) * 68 + (e & 63)]) = v;
    }
  }
  __syncthreads();

  if (tid < 225) {
    int py = tid / 15, px = tid - (tid / 15) * 15;
    float w0[9], w1[9];
#pragma unroll
    for (int j = 0; j < 9; j++) { w0[j] = wsm[j]; w1[j] = wsm[9 + j]; }
    const float b0 = wsm[18], b1v = wsm[19];
    float m0 = -1e30f, m1 = -1e30f;
    for (int dy = 0; dy < 4; dy++) {
      for (int dx = 0; dx < 4; dx++) {
        const float* ip = &img[(py * 4 + dy) * 68 + px * 4 + dx];
        float s0 = b0, s1 = b1v;
#pragma unroll
        for (int ky = 0; ky < 3; ky++) {
#pragma unroll
          for (int kx = 0; kx < 3; kx++) {
            float v = ip[ky * 68 + kx];
            s0 = fmaf(v, w0[ky * 3 + kx], s0);
            s1 = fmaf(v, w1[ky * 3 + kx], s1);
          }
        }
        m0 = fmaxf(m0, s0); m1 = fmaxf(m1, s1);
      }
    }
    p1[py * 16 + px] = fmaxf(m0, 0.f);
    p1[240 + py * 16 + px] = fmaxf(m1, 0.f);
  }
  __syncthreads();

  if (tid < 36) {
    int ch = tid / 9, rem = tid - ch * 9;
    int py = rem / 3, px = rem - py * 3;
    float m = -1e30f;
    for (int dy = 0; dy < 4; dy++) {
      for (int dx = 0; dx < 4; dx++) {
        int y = py * 4 + dy, xx = px * 4 + dx;
        float s = wsm[92 + ch];
#pragma unroll
        for (int ic = 0; ic < 2; ic++)
#pragma unroll
          for (int ky = 0; ky < 3; ky++)
#pragma unroll
            for (int kx = 0; kx < 3; kx++)
              s = fmaf(p1[ic * 240 + (y + ky) * 16 + xx + kx],
                       wsm[20 + ((ch * 2 + ic) * 3 + ky) * 3 + kx], s);
        m = fmaxf(m, s);
      }
    }
    p2[tid] = fmaxf(m, 0.f);
  }
  __syncthreads();

  float* fr = feat + ((long)t * B_ + b) * 16;
  if (tid < 8) {
    float s = fcb[tid];
#pragma unroll
    for (int j = 0; j < 36; j++) s = fmaf(p2[j], fcw[tid * 36 + j], s);
    fr[8 + tid] = s;
  } else if (tid < 16) {
    fr[tid - 8] = src[tid - 8];
  }
}

// ---------------------------------------------------------------------------
// Kernel 1b: pack ALL weight fragments to bf16 in the exact per-lane layout
// the lstm kernel consumes: frag F=((w*8+u)*9+kf), addr = F*512 + lane*8.
// kf 0..7: whh K-slice kf*32; kf 8: w_ih (K 0..15, rest zero).
// ---------------------------------------------------------------------------
__global__ __launch_bounds__(256) void pack_kernel(
    const float* __restrict__ whh, const float* __restrict__ wih,
    unsigned short* __restrict__ spack)
{
  const int idx = blockIdx.x * 256 + threadIdx.x;   // 0..36863
  const int lane = idx & 63;
  const int fragid = idx >> 6;                      // 0..575
  const int kf = fragid % 9;
  const int uw = fragid / 9;
  const int u = uw & 7, w = uw >> 3;
  const int col15 = lane & 15, ko8 = (lane >> 4) * 8;
  const int col = (u >> 1) * 256 + w * 32 + (u & 1) * 16 + col15;
  short8v v = {0, 0, 0, 0, 0, 0, 0, 0};
  if (kf < 8) {
    v = pack8(whh + col * 256 + kf * 32 + ko8);
  } else if (ko8 < 16) {
    v = pack8(wih + col * 16 + ko8);
  }
  *(short8v*)(spack + (size_t)idx * 8) = v;
}

// ---------------------------------------------------------------------------
// Kernel 2: LSTM, zero inter-block communication. 8 blocks x 512 thr (8 waves,
// 2/SIMD -> 256-VGPR cap). Wave w owns h-dims w*32..+31 for all 4 gates.
// Weights per wave = 72 frags, three tiers:
//   pinned VGPR : kf0..3 x u0..7            (32 frags, 128 regs, asm-pinned)
//   LDS         : kf4,kf5 x u0..7 + kf6 u0,1 (18 frags, 144 KB)
//   L2 stream   : kf6 u2..7 + kf7,kf8 x u0..7 (22 frags/step, 6 batches of 4,
//                 depth-2 issue/consume: peak ~8 frags = 32 regs in flight)
// i,f,g,o of each cell land in the same lane's acc -> in-register cell math.
// ---------------------------------------------------------------------------
__global__ __launch_bounds__(512, 2) void lstm_kernel(
    const float* __restrict__ feat, const float* __restrict__ bih,
    const float* __restrict__ bhh, const float* __restrict__ h0,
    const float* __restrict__ c0, const float* __restrict__ hw,
    const float* __restrict__ hdb, const unsigned short* __restrict__ spack,
    float* __restrict__ out)
{
  extern __shared__ char smem[];
  unsigned short* ldsB = (unsigned short*)smem;
  unsigned short* hls  = (unsigned short*)(smem + LDSB_BYTES);
  float* headp = (float*)(smem + LDSB_BYTES + HLS_BYTES);   // [8][20]

  const int tid = threadIdx.x;
  const int w = tid >> 6, lane = tid & 63;
  const int R0 = blockIdx.x * 16;
  const int col15 = lane & 15;
  const int ko8 = (lane >> 4) * 8;
  const int rb = (lane >> 4) * 4;
  const int Dw = w * 32;

  const unsigned short* sbase = spack + (size_t)(w * 8) * 9 * 512 + (size_t)lane * 8;
#define SFRAG(u, kf) (*(const short8v*)(sbase + ((u) * 9 + (kf)) * 512))

  // ---- pinned VGPR tier: kf0..3, all 8 gate-cols
  short8v bfr[8][4];
#pragma unroll
  for (int u = 0; u < 8; u++)
#pragma unroll
    for (int kf = 0; kf < 4; kf++)
      bfr[u][kf] = pinned(SFRAG(u, kf));

  // ---- LDS tier: s0..7 = kf4 u0..7, s8..15 = kf5 u0..7, s16,17 = kf6 u0,1
#pragma unroll
  for (int s = 0; s < 18; s++) {
    const int u = (s < 16) ? (s & 7) : (s - 16);
    const int kf = (s < 8) ? 4 : (s < 16) ? 5 : 6;
    *(short8v*)&ldsB[((w * 18 + s) * 64 + lane) * 8] = SFRAG(u, kf);
  }
#define LDSB(s) (*(const short8v*)&ldsB[((w * 18 + (s)) * 64 + lane) * 8])
#define HFRAG(kf) (*(const short8v*)&hls[ar * HLS_STRIDE + (kf) * 32 + ko8])

  // ---- per-lane constants
  float bsr[8];
#pragma unroll
  for (int u = 0; u < 8; u++) {
    const int col = (u >> 1) * 256 + Dw + (u & 1) * 16 + col15;
    bsr[u] = bih[col] + bhh[col];
  }
  float hwr[2] = { hw[Dw + col15], hw[Dw + 16 + col15] };
  const float hdb0 = hdb[0];

  // ---- c-state in registers; h0 -> padded LDS
  float cs[2][4];
#pragma unroll
  for (int q = 0; q < 2; q++)
#pragma unroll
    for (int rr = 0; rr < 4; rr++) {
      const int row = rb + rr, dim = Dw + q * 16 + col15;
      cs[q][rr] = c0[(R0 + row) * H_ + dim];
      hls[row * HLS_STRIDE + dim] = f2bf(h0[(R0 + row) * H_ + dim]);
    }

  const int ar = col15;   // A-fragment row (batch row in tile)

  for (int t = 0; t < T_; t++) {
    __syncthreads();   // h(t) & headp(t-1) ready

    // head output for step t-1
    if (w == 0 && lane < 16 && t > 0) {
      float s = hdb0;
#pragma unroll
      for (int i = 0; i < 8; i++) s += headp[i * 20 + lane];
      out[(long)(R0 + lane) * T_ + (t - 1)] = s;
    }

    // feat A-frag (issue early; consumed at the end)
    short8v af8 = (short8v){0, 0, 0, 0, 0, 0, 0, 0};
    if (ko8 < 16)
      af8 = pack8(feat + ((long)t * B_ + R0 + ar) * 16 + ko8);

    f32x4 acc[8];
#pragma unroll
    for (int u = 0; u < 8; u++) acc[u] = (f32x4){0.f, 0.f, 0.f, 0.f};

    // issue stream batch S0 (kf6 u2..5)
    short8v s00 = SFRAG(2, 6), s01 = SFRAG(3, 6), s02 = SFRAG(4, 6), s03 = SFRAG(5, 6);

    // pinned tier: kf0..3
#pragma unroll
    for (int kf = 0; kf < 4; kf++) {
      short8v a = HFRAG(kf);
#pragma unroll
      for (int u = 0; u < 8; u++)
        acc[u] = MFMA(a, bfr[u][kf], acc[u]);
    }

    // issue S1 (kf6 u6,7 ; kf7 u0,1)
    short8v s10 = SFRAG(6, 6), s11 = SFRAG(7, 6), s12 = SFRAG(0, 7), s13 = SFRAG(1, 7);

    // LDS tier kf4
    {
      short8v a4 = HFRAG(4);
#pragma unroll
      for (int u = 0; u < 8; u++)
        acc[u] = MFMA(a4, LDSB(u), acc[u]);
    }

    // consume S0
    short8v af6 = HFRAG(6);
    acc[2] = MFMA(af6, s00, acc[2]); acc[3] = MFMA(af6, s01, acc[3]);
    acc[4] = MFMA(af6, s02, acc[4]); acc[5] = MFMA(af6, s03, acc[5]);

    // issue S2 (kf7 u2..5)
    short8v s20 = SFRAG(2, 7), s21 = SFRAG(3, 7), s22 = SFRAG(4, 7), s23 = SFRAG(5, 7);

    // LDS tier kf5
    {
      short8v a5 = HFRAG(5);
#pragma unroll
      for (int u = 0; u < 8; u++)
        acc[u] = MFMA(a5, LDSB(8 + u), acc[u]);
    }

    // consume S1
    short8v af7 = HFRAG(7);
    acc[6] = MFMA(af6, s10, acc[6]); acc[7] = MFMA(af6, s11, acc[7]);
    acc[0] = MFMA(af7, s12, acc[0]); acc[1] = MFMA(af7, s13, acc[1]);

    // issue S3 (kf7 u6,7 ; kf8 u0,1)
    short8v s30 = SFRAG(6, 7), s31 = SFRAG(7, 7), s32 = SFRAG(0, 8), s33 = SFRAG(1, 8);

    // LDS tier kf6 u0,1
    acc[0] = MFMA(af6, LDSB(16), acc[0]);
    acc[1] = MFMA(af6, LDSB(17), acc[1]);

    // consume S2
    acc[2] = MFMA(af7, s20, acc[2]); acc[3] = MFMA(af7, s21, acc[3]);
    acc[4] = MFMA(af7, s22, acc[4]); acc[5] = MFMA(af7, s23, acc[5]);

    // issue S4 (kf8 u2..5)
    short8v s40 = SFRAG(2, 8), s41 = SFRAG(3, 8), s42 = SFRAG(4, 8), s43 = SFRAG(5, 8);

    // consume S3
    acc[6] = MFMA(af7, s30, acc[6]); acc[7] = MFMA(af7, s31, acc[7]);
    acc[0] = MFMA(af8, s32, acc[0]); acc[1] = MFMA(af8, s33, acc[1]);

    // issue S5 (kf8 u6,7) + consume S4, S5
    short8v s50 = SFRAG(6, 8), s51 = SFRAG(7, 8);
    acc[2] = MFMA(af8, s40, acc[2]); acc[3] = MFMA(af8, s41, acc[3]);
    acc[4] = MFMA(af8, s42, acc[4]); acc[5] = MFMA(af8, s43, acc[5]);
    acc[6] = MFMA(af8, s50, acc[6]); acc[7] = MFMA(af8, s51, acc[7]);

    __syncthreads();   // all reads of h(t)/headp done before overwrite

    // ---- in-register LSTM cell + h publish + head partial
    float ps[4] = {0.f, 0.f, 0.f, 0.f};
#pragma unroll
    for (int q = 0; q < 2; q++)
#pragma unroll
      for (int rr = 0; rr < 4; rr++) {
        float i_ = acc[0 + q][rr] + bsr[0 + q];
        float f_ = acc[2 + q][rr] + bsr[2 + q];
        float g_ = acc[4 + q][rr] + bsr[4 + q];
        float o_ = acc[6 + q][rr] + bsr[6 + q];
        float cn = sigm(f_) * cs[q][rr] + sigm(i_) * tanh_f(g_);
        cs[q][rr] = cn;
        float hn = sigm(o_) * tanh_f(cn);
        const int row = rb + rr, dim = Dw + q * 16 + col15;
        hls[row * HLS_STRIDE + dim] = f2bf(hn);
        ps[rr] += hn * hwr[q];
      }
#pragma unroll
    for (int off = 1; off <= 8; off <<= 1)
#pragma unroll
      for (int rr = 0; rr < 4; rr++) ps[rr] += __shfl_xor(ps[rr], off);
    if (col15 == 0)
#pragma unroll
      for (int rr = 0; rr < 4; rr++) headp[w * 20 + rb + rr] = ps[rr];
  }

  __syncthreads();
  if (w == 0 && lane < 16) {
    float s = hdb0;
#pragma unroll
    for (int i = 0; i < 8; i++) s += headp[i * 20 + lane];
    out[(long)(R0 + lane) * T_ + (T_ - 1)] = s;
  }
}

// ---------------------------------------------------------------------------
extern "C" void kernel_launch(void* const* d_in, const int* in_sizes, int n_in,
                              void* d_out, int out_size, void* d_ws, size_t ws_size,
                              hipStream_t stream) {
  const float* x   = (const float*)d_in[0];
  const float* c1w = (const float*)d_in[1];
  const float* c1b = (const float*)d_in[2];
  const float* c2w = (const float*)d_in[3];
  const float* c2b = (const float*)d_in[4];
  const float* fcw = (const float*)d_in[5];
  const float* fcb = (const float*)d_in[6];
  const float* wih = (const float*)d_in[7];
  const float* whh = (const float*)d_in[8];
  const float* bih = (const float*)d_in[9];
  const float* bhh = (const float*)d_in[10];
  const float* hw  = (const float*)d_in[11];
  const float* hdb = (const float*)d_in[12];
  const float* h0  = (const float*)d_in[13];
  const float* c0  = (const float*)d_in[14];
  float* out = (float*)d_out;

  char* ws = (char*)d_ws;
  const size_t FEAT_B = (size_t)T_ * B_ * 16 * 4;    // 2,211,840
  const size_t SPACK_B = (size_t)SPACK_SHORTS * 2;   // 589,824
  if (ws_size < FEAT_B + SPACK_B) return;
  float* feat = (float*)ws;
  unsigned short* spack = (unsigned short*)(ws + FEAT_B);

  hipFuncSetAttribute((const void*)lstm_kernel,
                      hipFuncAttributeMaxDynamicSharedMemorySize, SMEM_TOTAL);

  cnn_kernel<<<dim3(B_ * T_), dim3(256), 0, stream>>>(
      x, c1w, c1b, c2w, c2b, fcw, fcb, feat);
  pack_kernel<<<dim3(144), dim3(256), 0, stream>>>(whh, wih, spack);
  lstm_kernel<<<dim3(8), dim3(512), SMEM_TOTAL, stream>>>(
      feat, bih, bhh, h0, c0, hw, hdb, spack, out);
}

// Round 7
// 1456.708 us; speedup vs baseline: 2.1655x; 1.4295x over previous
//
#include <hip/hip_runtime.h>

#define B_ 128
#define T_ 270
#define XR 4104   // 8 + 64*64
#define H_ 256

typedef __attribute__((ext_vector_type(8))) short short8v;
typedef __attribute__((ext_vector_type(4))) float f32x4;

__device__ inline unsigned short f2bf(float f) {
  unsigned u = __builtin_bit_cast(unsigned, f);
  u += 0x7fffu + ((u >> 16) & 1u);
  return (unsigned short)(u >> 16);
}
__device__ inline float sigm(float x) { return 1.0f / (1.0f + __expf(-x)); }
__device__ inline float tanh_f(float x) {
  float t = __expf(-2.0f * fabsf(x));
  float r = (1.0f - t) / (1.0f + t);
  return copysignf(r, x);
}
__device__ inline short8v pack8(const float* p) {
  float4 a = *(const float4*)p, b = *(const float4*)(p + 4);
  short8v v;
  v[0] = (short)f2bf(a.x); v[1] = (short)f2bf(a.y);
  v[2] = (short)f2bf(a.z); v[3] = (short)f2bf(a.w);
  v[4] = (short)f2bf(b.x); v[5] = (short)f2bf(b.y);
  v[6] = (short)f2bf(b.z); v[7] = (short)f2bf(b.w);
  return v;
}
__device__ inline short8v pinned(short8v v) {
  union { short8v s; float f[4]; } u;
  u.s = v;
  asm volatile("" : "+v"(u.f[0]), "+v"(u.f[1]), "+v"(u.f[2]), "+v"(u.f[3]));
  return u.s;
}
#define MFMA(a, b, c) __builtin_amdgcn_mfma_f32_16x16x32_bf16((a), (b), (c), 0, 0, 0)

// ws layout (bytes)
#define FEAT16_B ((size_t)T_ * B_ * 16 * 2)        // 1,105,920
#define SPACK_B  ((size_t)8 * 8 * 9 * 64 * 8 * 2)  //   589,824
#define HB_B     ((size_t)2 * 16 * 16 * 128 * 2)   //   131,072 (2 bufs, 16 gid, 16 rows, 128 dims bf16)
#define HP_B     ((size_t)2 * 16 * 16 * 4 * 4)     //     8,192 (2 bufs, gid, row, wave) fp32
#define FLAGS_B  ((size_t)16 * 16 * 4)             //     1,024
#define WS_NEED  (FEAT16_B + SPACK_B + HB_B + HP_B + FLAGS_B)

// ---------------------------------------------------------------------------
// Kernel 1: per-(b,t) CNN tower. One block per image. Writes bf16 feat.
// Block 0 also re-zeroes the exchange flags (agent-scope, L3-visible).
// ---------------------------------------------------------------------------
__global__ __launch_bounds__(256) void cnn_kernel(
    const float* __restrict__ x,
    const float* __restrict__ c1w_, const float* __restrict__ c1b_,
    const float* __restrict__ c2w_, const float* __restrict__ c2b_,
    const float* __restrict__ fcw, const float* __restrict__ fcb,
    unsigned short* __restrict__ feat16, unsigned* __restrict__ flags)
{
  __shared__ float img[64 * 68];
  __shared__ float p1[2 * 15 * 16];
  __shared__ float p2[36];
  __shared__ float wsm[96];
  const int tid = threadIdx.x;
  const int bt = blockIdx.x;
  const int b = bt & 127, t = bt >> 7;

  if (bt == 0 && tid < 16)
    __hip_atomic_store(flags + tid * 16, 0u, __ATOMIC_RELAXED, __HIP_MEMORY_SCOPE_AGENT);

  const float* src = x + ((long)b * T_ + t) * XR;

  if (tid < 18) wsm[tid] = c1w_[tid];
  else if (tid < 20) wsm[tid] = c1b_[tid - 18];
  else if (tid < 92) wsm[tid] = c2w_[tid - 20];
  else if (tid < 96) wsm[tid] = c2b_[tid - 92];

  {
    const float4* s4 = (const float4*)(src + 8);
#pragma unroll
    for (int i0 = 0; i0 < 4; i0++) {
      int i = tid + i0 * 256;
      float4 v = s4[i];
      int e = i * 4;
      *((float4*)&img[(e >> 6) * 68 + (e & 63)]) = v;
    }
  }
  __syncthreads();

  if (tid < 225) {
    int py = tid / 15, px = tid - (tid / 15) * 15;
    float w0[9], w1[9];
#pragma unroll
    for (int j = 0; j < 9; j++) { w0[j] = wsm[j]; w1[j] = wsm[9 + j]; }
    const float b0 = wsm[18], b1v = wsm[19];
    float m0 = -1e30f, m1 = -1e30f;
    for (int dy = 0; dy < 4; dy++) {
      for (int dx = 0; dx < 4; dx++) {
        const float* ip = &img[(py * 4 + dy) * 68 + px * 4 + dx];
        float s0 = b0, s1 = b1v;
#pragma unroll
        for (int ky = 0; ky < 3; ky++) {
#pragma unroll
          for (int kx = 0; kx < 3; kx++) {
            float v = ip[ky * 68 + kx];
            s0 = fmaf(v, w0[ky * 3 + kx], s0);
            s1 = fmaf(v, w1[ky * 3 + kx], s1);
          }
        }
        m0 = fmaxf(m0, s0); m1 = fmaxf(m1, s1);
      }
    }
    p1[py * 16 + px] = fmaxf(m0, 0.f);
    p1[240 + py * 16 + px] = fmaxf(m1, 0.f);
  }
  __syncthreads();

  if (tid < 36) {
    int ch = tid / 9, rem = tid - ch * 9;
    int py = rem / 3, px = rem - py * 3;
    float m = -1e30f;
    for (int dy = 0; dy < 4; dy++) {
      for (int dx = 0; dx < 4; dx++) {
        int y = py * 4 + dy, xx = px * 4 + dx;
        float s = wsm[92 + ch];
#pragma unroll
        for (int ic = 0; ic < 2; ic++)
#pragma unroll
          for (int ky = 0; ky < 3; ky++)
#pragma unroll
            for (int kx = 0; kx < 3; kx++)
              s = fmaf(p1[ic * 240 + (y + ky) * 16 + xx + kx],
                       wsm[20 + ((ch * 2 + ic) * 3 + ky) * 3 + kx], s);
        m = fmaxf(m, s);
      }
    }
    p2[tid] = fmaxf(m, 0.f);
  }
  __syncthreads();

  unsigned short* fr = feat16 + ((long)t * B_ + b) * 16;
  if (tid < 8) {
    float s = fcb[tid];
#pragma unroll
    for (int j = 0; j < 36; j++) s = fmaf(p2[j], fcw[tid * 36 + j], s);
    fr[8 + tid] = f2bf(s);
  } else if (tid < 16) {
    fr[tid - 8] = f2bf(src[tid - 8]);
  }
}

// ---------------------------------------------------------------------------
// Kernel 1b: pack ALL weight fragments bf16 in the lstm's per-lane layout.
// fragid = ((hbk*4+w)*8 + u)*9 + s; addr = fragid*512 + lane*8 (shorts).
// cols: (u>>1)*256 + hbk*128 + w*32 + (u&1)*16 + (lane&15).
// s 0..3 = OWN h K-slices (kf = 4*hbk+s), s 4..7 = PEER (kf = 4*(1-hbk)+s-4),
// s 8 = w_ih (K 0..15, rest zero).
// ---------------------------------------------------------------------------
__global__ __launch_bounds__(256) void pack_kernel(
    const float* __restrict__ whh, const float* __restrict__ wih,
    unsigned short* __restrict__ spack)
{
  const int idx = blockIdx.x * 256 + threadIdx.x;   // 0..36863
  if (idx >= 8 * 8 * 9 * 64) return;
  const int lane = idx & 63;
  const int fragid = idx >> 6;          // 0..575
  const int s = fragid % 9;
  const int uw = fragid / 9;            // 0..63
  const int u = uw & 7;
  const int hw_ = uw >> 3;              // hbk*4 + w
  const int hbk = hw_ >> 2, w = hw_ & 3;
  const int col15 = lane & 15, ko8 = (lane >> 4) * 8;
  const int col = (u >> 1) * 256 + hbk * 128 + w * 32 + (u & 1) * 16 + col15;
  short8v v = {0, 0, 0, 0, 0, 0, 0, 0};
  if (s < 8) {
    const int kf = (s < 4) ? (4 * hbk + s) : (4 * (1 - hbk) + (s - 4));
    v = pack8(whh + col * 256 + kf * 32 + ko8);
  } else if (ko8 < 16) {
    v = pack8(wih + col * 16 + ko8);
  }
  *(short8v*)(spack + (size_t)idx * 8) = v;
}

// ---------------------------------------------------------------------------
// Kernel 2: LSTM. 16 blocks = 8 batch-groups x 2 hidden-halves; 256 thr
// (4 waves, 1/SIMD -> 512-VGPR cap). ALL 72 weight frags/wave VGPR-resident
// (288 regs; fits, unlike r4/r6's 256-cap configs). Pair exchange via L3
// atomics; all 8 peer loads issued back-to-back (r1/r3 serialized them per
// K-slot behind MFMAs -> ~6 RTT/step; this is 1). No atomicAdd anywhere.
// ---------------------------------------------------------------------------
__global__ __launch_bounds__(256, 1) void lstm_kernel(
    const unsigned short* __restrict__ feat16,
    const float* __restrict__ bih, const float* __restrict__ bhh,
    const float* __restrict__ h0, const float* __restrict__ c0,
    const float* __restrict__ hw, const float* __restrict__ hdb,
    const unsigned short* __restrict__ spack,
    unsigned short* hb16, float* hpg, unsigned* flags,
    float* __restrict__ out)
{
  __shared__ __attribute__((aligned(16))) unsigned short hls[16 * 136];
  __shared__ float hpw[4 * 16];
  const int tid = threadIdx.x;
  const int w = tid >> 6, lane = tid & 63;
  const int gb = blockIdx.x & 7, hbk = blockIdx.x >> 3;
  const int gid = gb * 2 + hbk, pgid = gb * 2 + (1 - hbk);
  const int R0 = gb * 16, D0 = hbk * 128;
  const int col15 = lane & 15, ko8 = (lane >> 4) * 8, rb = (lane >> 4) * 4;
  const int Dl = w * 32;                 // wave's local-dim base
  const int ar = col15;                  // A-frag row

  unsigned short* hbB[2] = { hb16, hb16 + 32768 };

  // ---- all-resident B fragments (pre-packed bf16, pinned against remat)
  const unsigned short* sbase =
      spack + (size_t)((hbk * 4 + w) * 8) * 9 * 512 + (size_t)lane * 8;
#define SFRAG(u, s) (*(const short8v*)(sbase + ((u) * 9 + (s)) * 512))
  short8v bfO[4][8], bfP[4][8], bfF[8];
#pragma unroll
  for (int u = 0; u < 8; u++) {
#pragma unroll
    for (int s = 0; s < 4; s++) bfO[s][u] = pinned(SFRAG(u, s));
#pragma unroll
    for (int s = 0; s < 4; s++) bfP[s][u] = pinned(SFRAG(u, 4 + s));
    bfF[u] = pinned(SFRAG(u, 8));
  }

  // ---- per-lane constants
  float bsr[8];
#pragma unroll
  for (int u = 0; u < 8; u++) {
    const int col = (u >> 1) * 256 + D0 + Dl + (u & 1) * 16 + col15;
    bsr[u] = bih[col] + bhh[col];
  }
  float hwr[2] = { hw[D0 + Dl + col15], hw[D0 + Dl + 16 + col15] };
  const float hdb0 = hdb[0];

  // ---- c-state in registers; h0 -> LDS + publish own half (buf 0)
  float cs[2][4];
#pragma unroll
  for (int q = 0; q < 2; q++)
#pragma unroll
    for (int rr = 0; rr < 4; rr++) {
      const int row = rb + rr, dloc = Dl + q * 16 + col15;
      cs[q][rr] = c0[(R0 + row) * H_ + D0 + dloc];
      unsigned short hv = f2bf(h0[(R0 + row) * H_ + D0 + dloc]);
      hls[row * 136 + dloc] = hv;
      __hip_atomic_store(hbB[0] + (gid * 16 + row) * 128 + dloc, hv,
                         __ATOMIC_RELAXED, __HIP_MEMORY_SCOPE_AGENT);
    }
  __syncthreads();   // drains vmcnt: h0 publish acked before flag
  if (tid == 0)
    __hip_atomic_store(flags + gid * 16, 1u, __ATOMIC_RELEASE, __HIP_MEMORY_SCOPE_AGENT);

  const unsigned* pflag = flags + pgid * 16;

  for (int t = 0; t < T_; t++) {
    // ---- own A-frags (LDS) + feat frag; own+feat MFMAs overlap the wait
    short8v af8 = (short8v){0, 0, 0, 0, 0, 0, 0, 0};
    if (ko8 < 16)
      af8 = *(const short8v*)(feat16 + ((size_t)t * B_ + R0 + ar) * 16 + ko8);

    f32x4 acc[8];
#pragma unroll
    for (int u = 0; u < 8; u++) acc[u] = (f32x4){0.f, 0.f, 0.f, 0.f};
#pragma unroll
    for (int s = 0; s < 4; s++) {
      short8v a = *(const short8v*)&hls[ar * 136 + s * 32 + ko8];
#pragma unroll
      for (int u = 0; u < 8; u++) acc[u] = MFMA(a, bfO[s][u], acc[u]);
    }
#pragma unroll
    for (int u = 0; u < 8; u++) acc[u] = MFMA(af8, bfF[u], acc[u]);

    // ---- wait for peer h(t)
    {
      const unsigned need = (unsigned)(t + 1);
      unsigned v; long guard = 0;
      do {
        v = __hip_atomic_load(pflag, __ATOMIC_RELAXED, __HIP_MEMORY_SCOPE_AGENT);
      } while (v < need && ++guard < (1L << 22));
      __builtin_amdgcn_fence(__ATOMIC_ACQUIRE, "agent");
    }

    // ---- out[t-1] (block half 0 only): own partials (LDS) + peer partials
    if (hbk == 0 && tid < 16 && t > 0) {
      float s = hdb0 + hpw[tid] + hpw[16 + tid] + hpw[32 + tid] + hpw[48 + tid];
      const float* pp = hpg + (t & 1) * 1024 + pgid * 64 + tid * 4;
#pragma unroll
      for (int i = 0; i < 4; i++)
        s += __hip_atomic_load(pp + i, __ATOMIC_RELAXED, __HIP_MEMORY_SCOPE_AGENT);
      out[(long)(R0 + tid) * T_ + (t - 1)] = s;
    }

    // ---- peer h loads: ALL EIGHT issued back-to-back (1 RTT), then MFMAs
    const unsigned long long* hbr = (const unsigned long long*)hbB[t & 1];
    unsigned long long pq[8];
#pragma unroll
    for (int s = 0; s < 4; s++) {
      const unsigned long long* pr =
          hbr + (size_t)(pgid * 16 + ar) * 32 + s * 8 + (ko8 >> 2);
      pq[2 * s]     = __hip_atomic_load(pr,     __ATOMIC_RELAXED, __HIP_MEMORY_SCOPE_AGENT);
      pq[2 * s + 1] = __hip_atomic_load(pr + 1, __ATOMIC_RELAXED, __HIP_MEMORY_SCOPE_AGENT);
    }
#pragma unroll
    for (int s = 0; s < 4; s++) {
      union { unsigned long long q[2]; short8v v; } u_;
      u_.q[0] = pq[2 * s]; u_.q[1] = pq[2 * s + 1];
#pragma unroll
      for (int u = 0; u < 8; u++) acc[u] = MFMA(u_.v, bfP[s][u], acc[u]);
    }

    __syncthreads();   // all hls/hpw reads of this step done

    // ---- in-register LSTM cell + publishes
    unsigned short* hbw = hbB[(t + 1) & 1];
    float ps[4] = {0.f, 0.f, 0.f, 0.f};
#pragma unroll
    for (int q = 0; q < 2; q++)
#pragma unroll
      for (int rr = 0; rr < 4; rr++) {
        float i_ = acc[0 + q][rr] + bsr[0 + q];
        float f_ = acc[2 + q][rr] + bsr[2 + q];
        float g_ = acc[4 + q][rr] + bsr[4 + q];
        float o_ = acc[6 + q][rr] + bsr[6 + q];
        float cn = sigm(f_) * cs[q][rr] + sigm(i_) * tanh_f(g_);
        cs[q][rr] = cn;
        float hn = sigm(o_) * tanh_f(cn);
        const int row = rb + rr, dloc = Dl + q * 16 + col15;
        unsigned short hv = f2bf(hn);
        hls[row * 136 + dloc] = hv;
        __hip_atomic_store(hbw + (gid * 16 + row) * 128 + dloc, hv,
                           __ATOMIC_RELAXED, __HIP_MEMORY_SCOPE_AGENT);
        ps[rr] += hn * hwr[q];
      }
#pragma unroll
    for (int off = 1; off <= 8; off <<= 1)
#pragma unroll
      for (int rr = 0; rr < 4; rr++) ps[rr] += __shfl_xor(ps[rr], off);
    if (col15 == 0) {
#pragma unroll
      for (int rr = 0; rr < 4; rr++) {
        hpw[w * 16 + rb + rr] = ps[rr];
        __hip_atomic_store(hpg + ((t + 1) & 1) * 1024 + gid * 64 + (rb + rr) * 4 + w,
                           ps[rr], __ATOMIC_RELAXED, __HIP_MEMORY_SCOPE_AGENT);
      }
    }

    __syncthreads();   // drains vmcnt: h(t+1)/hp publishes acked
    if (tid == 0)
      __hip_atomic_store(flags + gid * 16, (unsigned)(t + 2),
                         __ATOMIC_RELEASE, __HIP_MEMORY_SCOPE_AGENT);
  }

  // ---- final output column (t = T-1) from h(T), hp(T)
  if (hbk == 0) {
    {
      const unsigned need = (unsigned)(T_ + 1);
      unsigned v; long guard = 0;
      do {
        v = __hip_atomic_load(pflag, __ATOMIC_RELAXED, __HIP_MEMORY_SCOPE_AGENT);
      } while (v < need && ++guard < (1L << 22));
      __builtin_amdgcn_fence(__ATOMIC_ACQUIRE, "agent");
    }
    if (tid < 16) {
      float s = hdb0 + hpw[tid] + hpw[16 + tid] + hpw[32 + tid] + hpw[48 + tid];
      const float* pp = hpg + (T_ & 1) * 1024 + pgid * 64 + tid * 4;
#pragma unroll
      for (int i = 0; i < 4; i++)
        s += __hip_atomic_load(pp + i, __ATOMIC_RELAXED, __HIP_MEMORY_SCOPE_AGENT);
      out[(long)(R0 + tid) * T_ + (T_ - 1)] = s;
    }
  }
}

// ---------------------------------------------------------------------------
extern "C" void kernel_launch(void* const* d_in, const int* in_sizes, int n_in,
                              void* d_out, int out_size, void* d_ws, size_t ws_size,
                              hipStream_t stream) {
  const float* x   = (const float*)d_in[0];
  const float* c1w = (const float*)d_in[1];
  const float* c1b = (const float*)d_in[2];
  const float* c2w = (const float*)d_in[3];
  const float* c2b = (const float*)d_in[4];
  const float* fcw = (const float*)d_in[5];
  const float* fcb = (const float*)d_in[6];
  const float* wih = (const float*)d_in[7];
  const float* whh = (const float*)d_in[8];
  const float* bih = (const float*)d_in[9];
  const float* bhh = (const float*)d_in[10];
  const float* hw  = (const float*)d_in[11];
  const float* hdb = (const float*)d_in[12];
  const float* h0  = (const float*)d_in[13];
  const float* c0  = (const float*)d_in[14];
  float* out = (float*)d_out;

  if (ws_size < WS_NEED) return;
  char* ws = (char*)d_ws;
  unsigned short* feat16 = (unsigned short*)ws;
  unsigned short* spack  = (unsigned short*)(ws + FEAT16_B);
  unsigned short* hb16   = (unsigned short*)(ws + FEAT16_B + SPACK_B);
  float* hpg             = (float*)(ws + FEAT16_B + SPACK_B + HB_B);
  unsigned* flags        = (unsigned*)(ws + FEAT16_B + SPACK_B + HB_B + HP_B);

  cnn_kernel<<<dim3(B_ * T_), dim3(256), 0, stream>>>(
      x, c1w, c1b, c2w, c2b, fcw, fcb, feat16, flags);
  pack_kernel<<<dim3(144), dim3(256), 0, stream>>>(whh, wih, spack);
  lstm_kernel<<<dim3(16), dim3(256), 0, stream>>>(
      feat16, bih, bhh, h0, c0, hw, hdb, spack, hb16, hpg, flags, out);
}

// Round 8
// 1452.377 us; speedup vs baseline: 2.1719x; 1.0030x over previous
//
#include <hip/hip_runtime.h>

#define B_ 128
#define T_ 270
#define XR 4104   // 8 + 64*64
#define H_ 256

typedef __attribute__((ext_vector_type(8))) short short8v;
typedef __attribute__((ext_vector_type(4))) float f32x4;

__device__ inline unsigned short f2bf(float f) {
  unsigned u = __builtin_bit_cast(unsigned, f);
  u += 0x7fffu + ((u >> 16) & 1u);
  return (unsigned short)(u >> 16);
}
__device__ inline float sigm(float x) { return 1.0f / (1.0f + __expf(-x)); }
__device__ inline float tanh_f(float x) {
  float t = __expf(-2.0f * fabsf(x));
  float r = (1.0f - t) / (1.0f + t);
  return copysignf(r, x);
}
__device__ inline short8v pack8(const float* p) {
  float4 a = *(const float4*)p, b = *(const float4*)(p + 4);
  short8v v;
  v[0] = (short)f2bf(a.x); v[1] = (short)f2bf(a.y);
  v[2] = (short)f2bf(a.z); v[3] = (short)f2bf(a.w);
  v[4] = (short)f2bf(b.x); v[5] = (short)f2bf(b.y);
  v[6] = (short)f2bf(b.z); v[7] = (short)f2bf(b.w);
  return v;
}
// Arch-VGPR pin (max 256 of these per wave!)
__device__ inline short8v pinned(short8v v) {
  union { short8v s; float f[4]; } u;
  u.s = v;
  asm volatile("" : "+v"(u.f[0]), "+v"(u.f[1]), "+v"(u.f[2]), "+v"(u.f[3]));
  return u.s;
}
// AGPR pin — MFMA reads A/B operands from AGPRs natively on gfx950 (ISA §10),
// so these 128 regs live in the accumulator file and don't touch the 256-cap
// arch file (round-7 failure: 288 "+v"-pinned regs > 256 arch cap -> spill).
__device__ inline short8v pinned_a(short8v v) {
  union { short8v s; float f[4]; } u;
  u.s = v;
  asm volatile("" : "+a"(u.f[0]), "+a"(u.f[1]), "+a"(u.f[2]), "+a"(u.f[3]));
  return u.s;
}
#define MFMA(a, b, c) __builtin_amdgcn_mfma_f32_16x16x32_bf16((a), (b), (c), 0, 0, 0)

// ws layout (bytes)
#define FEAT16_B ((size_t)T_ * B_ * 16 * 2)        // 1,105,920
#define SPACK_B  ((size_t)8 * 8 * 9 * 64 * 8 * 2)  //   589,824
#define HB_B     ((size_t)2 * 16 * 16 * 128 * 2)   //   131,072
#define HP_B     ((size_t)2 * 16 * 16 * 4 * 4)     //     8,192
#define FLAGS_B  ((size_t)64 * 16 * 4)             //     4,096 (16 blocks x 4 waves)
#define WS_NEED  (FEAT16_B + SPACK_B + HB_B + HP_B + FLAGS_B)

// ---------------------------------------------------------------------------
// Kernel 1: per-(b,t) CNN tower. One block per image. Writes bf16 feat.
// Block 0 re-zeroes the 64 per-wave exchange flags.
// ---------------------------------------------------------------------------
__global__ __launch_bounds__(256) void cnn_kernel(
    const float* __restrict__ x,
    const float* __restrict__ c1w_, const float* __restrict__ c1b_,
    const float* __restrict__ c2w_, const float* __restrict__ c2b_,
    const float* __restrict__ fcw, const float* __restrict__ fcb,
    unsigned short* __restrict__ feat16, unsigned* __restrict__ flags)
{
  __shared__ float img[64 * 68];
  __shared__ float p1[2 * 15 * 16];
  __shared__ float p2[36];
  __shared__ float wsm[96];
  const int tid = threadIdx.x;
  const int bt = blockIdx.x;
  const int b = bt & 127, t = bt >> 7;

  if (bt == 0 && tid < 64)
    __hip_atomic_store(flags + tid * 16, 0u, __ATOMIC_RELAXED, __HIP_MEMORY_SCOPE_AGENT);

  const float* src = x + ((long)b * T_ + t) * XR;

  if (tid < 18) wsm[tid] = c1w_[tid];
  else if (tid < 20) wsm[tid] = c1b_[tid - 18];
  else if (tid < 92) wsm[tid] = c2w_[tid - 20];
  else if (tid < 96) wsm[tid] = c2b_[tid - 92];

  {
    const float4* s4 = (const float4*)(src + 8);
#pragma unroll
    for (int i0 = 0; i0 < 4; i0++) {
      int i = tid + i0 * 256;
      float4 v = s4[i];
      int e = i * 4;
      *((float4*)&img[(e >> 6) * 68 + (e & 63)]) = v;
    }
  }
  __syncthreads();

  if (tid < 225) {
    int py = tid / 15, px = tid - (tid / 15) * 15;
    float w0[9], w1[9];
#pragma unroll
    for (int j = 0; j < 9; j++) { w0[j] = wsm[j]; w1[j] = wsm[9 + j]; }
    const float b0 = wsm[18], b1v = wsm[19];
    float m0 = -1e30f, m1 = -1e30f;
    for (int dy = 0; dy < 4; dy++) {
      for (int dx = 0; dx < 4; dx++) {
        const float* ip = &img[(py * 4 + dy) * 68 + px * 4 + dx];
        float s0 = b0, s1 = b1v;
#pragma unroll
        for (int ky = 0; ky < 3; ky++) {
#pragma unroll
          for (int kx = 0; kx < 3; kx++) {
            float v = ip[ky * 68 + kx];
            s0 = fmaf(v, w0[ky * 3 + kx], s0);
            s1 = fmaf(v, w1[ky * 3 + kx], s1);
          }
        }
        m0 = fmaxf(m0, s0); m1 = fmaxf(m1, s1);
      }
    }
    p1[py * 16 + px] = fmaxf(m0, 0.f);
    p1[240 + py * 16 + px] = fmaxf(m1, 0.f);
  }
  __syncthreads();

  if (tid < 36) {
    int ch = tid / 9, rem = tid - ch * 9;
    int py = rem / 3, px = rem - py * 3;
    float m = -1e30f;
    for (int dy = 0; dy < 4; dy++) {
      for (int dx = 0; dx < 4; dx++) {
        int y = py * 4 + dy, xx = px * 4 + dx;
        float s = wsm[92 + ch];
#pragma unroll
        for (int ic = 0; ic < 2; ic++)
#pragma unroll
          for (int ky = 0; ky < 3; ky++)
#pragma unroll
            for (int kx = 0; kx < 3; kx++)
              s = fmaf(p1[ic * 240 + (y + ky) * 16 + xx + kx],
                       wsm[20 + ((ch * 2 + ic) * 3 + ky) * 3 + kx], s);
        m = fmaxf(m, s);
      }
    }
    p2[tid] = fmaxf(m, 0.f);
  }
  __syncthreads();

  unsigned short* fr = feat16 + ((long)t * B_ + b) * 16;
  if (tid < 8) {
    float s = fcb[tid];
#pragma unroll
    for (int j = 0; j < 36; j++) s = fmaf(p2[j], fcw[tid * 36 + j], s);
    fr[8 + tid] = f2bf(s);
  } else if (tid < 16) {
    fr[tid - 8] = f2bf(src[tid - 8]);
  }
}

// ---------------------------------------------------------------------------
// Kernel 1b: pack ALL weight fragments bf16 (unchanged from round 7).
// ---------------------------------------------------------------------------
__global__ __launch_bounds__(256) void pack_kernel(
    const float* __restrict__ whh, const float* __restrict__ wih,
    unsigned short* __restrict__ spack)
{
  const int idx = blockIdx.x * 256 + threadIdx.x;   // 0..36863
  if (idx >= 8 * 8 * 9 * 64) return;
  const int lane = idx & 63;
  const int fragid = idx >> 6;          // 0..575
  const int s = fragid % 9;
  const int uw = fragid / 9;            // 0..63
  const int u = uw & 7;
  const int hw_ = uw >> 3;              // hbk*4 + w
  const int hbk = hw_ >> 2, w = hw_ & 3;
  const int col15 = lane & 15, ko8 = (lane >> 4) * 8;
  const int col = (u >> 1) * 256 + hbk * 128 + w * 32 + (u & 1) * 16 + col15;
  short8v v = {0, 0, 0, 0, 0, 0, 0, 0};
  if (s < 8) {
    const int kf = (s < 4) ? (4 * hbk + s) : (4 * (1 - hbk) + (s - 4));
    v = pack8(whh + col * 256 + kf * 32 + ko8);
  } else if (ko8 < 16) {
    v = pack8(wih + col * 16 + ko8);
  }
  *(short8v*)(spack + (size_t)idx * 8) = v;
}

// ---------------------------------------------------------------------------
// Kernel 2: LSTM. 16 blocks = 8 batch-groups x 2 hidden-halves; 256 thr
// (4 waves, 1 wave/SIMD). Weight residency split across register files:
//   bfO (own-h, 32 frags, 128 regs)  -> AGPR-pinned
//   bfP (peer-h, 32 frags) + bfF (8) -> arch-VGPR-pinned (160 regs)
// => arch ~230 <= 256, AGPR ~160 <= 256: NO SPILL (r7: 220 VGPR = spill).
// Pair exchange via L3 atomics, 8 peer loads back-to-back (1 RTT).
// Per-WAVE release flags: each wave releases its own sub-flag right after its
// publish stores (no block barrier on the flag path).
// ---------------------------------------------------------------------------
__global__ __launch_bounds__(256, 1) void lstm_kernel(
    const unsigned short* __restrict__ feat16,
    const float* __restrict__ bih, const float* __restrict__ bhh,
    const float* __restrict__ h0, const float* __restrict__ c0,
    const float* __restrict__ hw, const float* __restrict__ hdb,
    const unsigned short* __restrict__ spack,
    unsigned short* hb16, float* hpg, unsigned* flags,
    float* __restrict__ out)
{
  __shared__ __attribute__((aligned(16))) unsigned short hls[16 * 136];
  __shared__ float hpw[4 * 16];
  const int tid = threadIdx.x;
  const int w = tid >> 6, lane = tid & 63;
  const int gb = blockIdx.x & 7, hbk = blockIdx.x >> 3;
  const int gid = gb * 2 + hbk, pgid = gb * 2 + (1 - hbk);
  const int R0 = gb * 16, D0 = hbk * 128;
  const int col15 = lane & 15, ko8 = (lane >> 4) * 8, rb = (lane >> 4) * 4;
  const int Dl = w * 32;
  const int ar = col15;

  unsigned short* hbB[2] = { hb16, hb16 + 32768 };

  const unsigned short* sbase =
      spack + (size_t)((hbk * 4 + w) * 8) * 9 * 512 + (size_t)lane * 8;
#define SFRAG(u, s) (*(const short8v*)(sbase + ((u) * 9 + (s)) * 512))
  short8v bfO[4][8], bfP[4][8], bfF[8];
#pragma unroll
  for (int u = 0; u < 8; u++) {
#pragma unroll
    for (int s = 0; s < 4; s++) bfO[s][u] = pinned_a(SFRAG(u, s));   // AGPR
#pragma unroll
    for (int s = 0; s < 4; s++) bfP[s][u] = pinned(SFRAG(u, 4 + s)); // VGPR
    bfF[u] = pinned(SFRAG(u, 8));                                    // VGPR
  }

  float bsr[8];
#pragma unroll
  for (int u = 0; u < 8; u++) {
    const int col = (u >> 1) * 256 + D0 + Dl + (u & 1) * 16 + col15;
    bsr[u] = bih[col] + bhh[col];
  }
  float hwr[2] = { hw[D0 + Dl + col15], hw[D0 + Dl + 16 + col15] };
  const float hdb0 = hdb[0];

  // ---- c-state; h0 -> LDS + publish own half (buf 0); per-wave flag release
  float cs[2][4];
#pragma unroll
  for (int q = 0; q < 2; q++)
#pragma unroll
    for (int rr = 0; rr < 4; rr++) {
      const int row = rb + rr, dloc = Dl + q * 16 + col15;
      cs[q][rr] = c0[(R0 + row) * H_ + D0 + dloc];
      unsigned short hv = f2bf(h0[(R0 + row) * H_ + D0 + dloc]);
      hls[row * 136 + dloc] = hv;
      __hip_atomic_store(hbB[0] + (gid * 16 + row) * 128 + dloc, hv,
                         __ATOMIC_RELAXED, __HIP_MEMORY_SCOPE_AGENT);
    }
  if (lane == 0)   // release: orders THIS wave's h0 stores before the flag
    __hip_atomic_store(flags + (gid * 4 + w) * 16, 1u,
                       __ATOMIC_RELEASE, __HIP_MEMORY_SCOPE_AGENT);
  __syncthreads();   // hls(0) complete for all waves

  for (int t = 0; t < T_; t++) {
    // ---- feat + own-half MFMAs (overlap peer's publish latency)
    short8v af8 = (short8v){0, 0, 0, 0, 0, 0, 0, 0};
    if (ko8 < 16)
      af8 = *(const short8v*)(feat16 + ((size_t)t * B_ + R0 + ar) * 16 + ko8);

    f32x4 acc[8];
#pragma unroll
    for (int u = 0; u < 8; u++) acc[u] = (f32x4){0.f, 0.f, 0.f, 0.f};
#pragma unroll
    for (int s = 0; s < 4; s++) {
      short8v a = *(const short8v*)&hls[ar * 136 + s * 32 + ko8];
#pragma unroll
      for (int u = 0; u < 8; u++) acc[u] = MFMA(a, bfO[s][u], acc[u]);
    }
#pragma unroll
    for (int u = 0; u < 8; u++) acc[u] = MFMA(af8, bfF[u], acc[u]);

    // ---- wait for all 4 peer waves' flags >= t+1 (4 lanes poll, __all)
    {
      const unsigned need = (unsigned)(t + 1);
      const unsigned* pp = flags + (pgid * 4 + (lane & 3)) * 16;
      bool ok; long guard = 0;
      do {
        unsigned v = (lane < 4)
            ? __hip_atomic_load(pp, __ATOMIC_RELAXED, __HIP_MEMORY_SCOPE_AGENT)
            : need;
        ok = __all((int)(v >= need));
      } while (!ok && ++guard < (1L << 22));
      __builtin_amdgcn_fence(__ATOMIC_ACQUIRE, "agent");
    }

    // ---- out[t-1] (half-0 block only)
    if (hbk == 0 && tid < 16 && t > 0) {
      float s = hdb0 + hpw[tid] + hpw[16 + tid] + hpw[32 + tid] + hpw[48 + tid];
      const float* pp = hpg + (t & 1) * 1024 + pgid * 64 + tid * 4;
#pragma unroll
      for (int i = 0; i < 4; i++)
        s += __hip_atomic_load(pp + i, __ATOMIC_RELAXED, __HIP_MEMORY_SCOPE_AGENT);
      out[(long)(R0 + tid) * T_ + (t - 1)] = s;
    }

    // ---- peer h loads: ALL EIGHT back-to-back (1 RTT), then MFMAs
    const unsigned long long* hbr = (const unsigned long long*)hbB[t & 1];
    unsigned long long pq[8];
#pragma unroll
    for (int s = 0; s < 4; s++) {
      const unsigned long long* pr =
          hbr + (size_t)(pgid * 16 + ar) * 32 + s * 8 + (ko8 >> 2);
      pq[2 * s]     = __hip_atomic_load(pr,     __ATOMIC_RELAXED, __HIP_MEMORY_SCOPE_AGENT);
      pq[2 * s + 1] = __hip_atomic_load(pr + 1, __ATOMIC_RELAXED, __HIP_MEMORY_SCOPE_AGENT);
    }
#pragma unroll
    for (int s = 0; s < 4; s++) {
      union { unsigned long long q[2]; short8v v; } u_;
      u_.q[0] = pq[2 * s]; u_.q[1] = pq[2 * s + 1];
#pragma unroll
      for (int u = 0; u < 8; u++) acc[u] = MFMA(u_.v, bfP[s][u], acc[u]);
    }

    __syncthreads();   // all hls/hpw reads of this step done

    // ---- in-register LSTM cell + publishes
    unsigned short* hbw = hbB[(t + 1) & 1];
    float ps[4] = {0.f, 0.f, 0.f, 0.f};
#pragma unroll
    for (int q = 0; q < 2; q++)
#pragma unroll
      for (int rr = 0; rr < 4; rr++) {
        float i_ = acc[0 + q][rr] + bsr[0 + q];
        float f_ = acc[2 + q][rr] + bsr[2 + q];
        float g_ = acc[4 + q][rr] + bsr[4 + q];
        float o_ = acc[6 + q][rr] + bsr[6 + q];
        float cn = sigm(f_) * cs[q][rr] + sigm(i_) * tanh_f(g_);
        cs[q][rr] = cn;
        float hn = sigm(o_) * tanh_f(cn);
        const int row = rb + rr, dloc = Dl + q * 16 + col15;
        unsigned short hv = f2bf(hn);
        hls[row * 136 + dloc] = hv;
        __hip_atomic_store(hbw + (gid * 16 + row) * 128 + dloc, hv,
                           __ATOMIC_RELAXED, __HIP_MEMORY_SCOPE_AGENT);
        ps[rr] += hn * hwr[q];
      }
#pragma unroll
    for (int off = 1; off <= 8; off <<= 1)
#pragma unroll
      for (int rr = 0; rr < 4; rr++) ps[rr] += __shfl_xor(ps[rr], off);
    if (col15 == 0) {
#pragma unroll
      for (int rr = 0; rr < 4; rr++) {
        hpw[w * 16 + rb + rr] = ps[rr];
        __hip_atomic_store(hpg + ((t + 1) & 1) * 1024 + gid * 64 + (rb + rr) * 4 + w,
                           ps[rr], __ATOMIC_RELAXED, __HIP_MEMORY_SCOPE_AGENT);
      }
    }

    // per-wave release: orders this wave's h(t+1)/hp stores before its flag
    if (lane == 0)
      __hip_atomic_store(flags + (gid * 4 + w) * 16, (unsigned)(t + 2),
                         __ATOMIC_RELEASE, __HIP_MEMORY_SCOPE_AGENT);
    __syncthreads();   // hls(t+1)/hpw visible block-wide for next step
  }

  // ---- final output column (t = T-1)
  if (hbk == 0) {
    {
      const unsigned need = (unsigned)(T_ + 1);
      const unsigned* pp = flags + (pgid * 4 + (lane & 3)) * 16;
      bool ok; long guard = 0;
      do {
        unsigned v = (lane < 4)
            ? __hip_atomic_load(pp, __ATOMIC_RELAXED, __HIP_MEMORY_SCOPE_AGENT)
            : need;
        ok = __all((int)(v >= need));
      } while (!ok && ++guard < (1L << 22));
      __builtin_amdgcn_fence(__ATOMIC_ACQUIRE, "agent");
    }
    if (tid < 16) {
      float s = hdb0 + hpw[tid] + hpw[16 + tid] + hpw[32 + tid] + hpw[48 + tid];
      const float* pp = hpg + (T_ & 1) * 1024 + pgid * 64 + tid * 4;
#pragma unroll
      for (int i = 0; i < 4; i++)
        s += __hip_atomic_load(pp + i, __ATOMIC_RELAXED, __HIP_MEMORY_SCOPE_AGENT);
      out[(long)(R0 + tid) * T_ + (T_ - 1)] = s;
    }
  }
}

// ---------------------------------------------------------------------------
extern "C" void kernel_launch(void* const* d_in, const int* in_sizes, int n_in,
                              void* d_out, int out_size, void* d_ws, size_t ws_size,
                              hipStream_t stream) {
  const float* x   = (const float*)d_in[0];
  const float* c1w = (const float*)d_in[1];
  const float* c1b = (const float*)d_in[2];
  const float* c2w = (const float*)d_in[3];
  const float* c2b = (const float*)d_in[4];
  const float* fcw = (const float*)d_in[5];
  const float* fcb = (const float*)d_in[6];
  const float* wih = (const float*)d_in[7];
  const float* whh = (const float*)d_in[8];
  const float* bih = (const float*)d_in[9];
  const float* bhh = (const float*)d_in[10];
  const float* hw  = (const float*)d_in[11];
  const float* hdb = (const float*)d_in[12];
  const float* h0  = (const float*)d_in[13];
  const float* c0  = (const float*)d_in[14];
  float* out = (float*)d_out;

  if (ws_size < WS_NEED) return;
  char* ws = (char*)d_ws;
  unsigned short* feat16 = (unsigned short*)ws;
  unsigned short* spack  = (unsigned short*)(ws + FEAT16_B);
  unsigned short* hb16   = (unsigned short*)(ws + FEAT16_B + SPACK_B);
  float* hpg             = (float*)(ws + FEAT16_B + SPACK_B + HB_B);
  unsigned* flags        = (unsigned*)(ws + FEAT16_B + SPACK_B + HB_B + HP_B);

  cnn_kernel<<<dim3(B_ * T_), dim3(256), 0, stream>>>(
      x, c1w, c1b, c2w, c2b, fcw, fcb, feat16, flags);
  pack_kernel<<<dim3(144), dim3(256), 0, stream>>>(whh, wih, spack);
  lstm_kernel<<<dim3(16), dim3(256), 0, stream>>>(
      feat16, bih, bhh, h0, c0, hw, hdb, spack, hb16, hpg, flags, out);
}